// Round 21
// baseline (77.287 us; speedup 1.0000x reference)
//
#include <hip/hip_runtime.h>
#include <math.h>

#define NROWS 65536
#define D     64
#define K     1024
#define NCT   8            // code tiles (K/128)
#define BR    128
#define BC    128
#define BETA  0.25f
#define SCALE 1024.0f      // pow2 -> exact f32 scaling; keeps xl/el f16-normal
#define THR   200.0f       // scaled-dist margin (R15-proven)
#define FXS   1048576.0    // fixed-point scale 2^20 for deterministic loss sum

typedef _Float16 half8  __attribute__((ext_vector_type(8)));
typedef float    f32x4  __attribute__((ext_vector_type(4)));
typedef unsigned long long u64;

// ws layout (bytes)
// Bp fragment-linear: [ct:32768][h:16384][kk:8192][ci:1024][lane:16]
//   lane = kg*16 + fr holds f16 elems [kk*32+kg*8, +8) of code ct*128+ci*16+fr
#define WS_BP   0u                         // 256 KB
#define WS_EN   (256u*1024)                // f32 [K] enorm (4 KB)
#define WS_EN2  (260u*1024)                // f32 [K] enorm*S^2 (4 KB)
#define WS_LIST (264u*1024)                // u32 [NROWS] (256 KB)
#define WS_CNT  (WS_LIST + 256u*1024)      // u32 counter (pad 128)
#define WS_ERR  (WS_CNT + 128u)            // u64 fixed-point err accumulator

static __device__ __forceinline__ unsigned ordf(float f) {
    unsigned b = __float_as_uint(f);
    return (b & 0x80000000u) ? ~b : (b | 0x80000000u);
}

// ------------------- prep: enorm + fragment-linear packed B + accum resets --
__global__ __launch_bounds__(256) void vq_prep(const float* __restrict__ emb,
                                               float* __restrict__ enorm,
                                               float* __restrict__ enorm2,
                                               char* __restrict__ Bp,
                                               unsigned* __restrict__ counter,
                                               u64* __restrict__ errAcc) {
    if (blockIdx.x == 0 && threadIdx.x == 0) { counter[0] = 0u; errAcc[0] = 0ull; }
    int k = blockIdx.x * 256 + threadIdx.x;
    if (k >= K) return;
    const int ct  = k >> 7;
    const int ci  = (k & 127) >> 4;
    const int frk = k & 15;
    char* tbase = Bp + (size_t)ct * 32768;
    const float4* e4 = (const float4*)(emb + (size_t)k * D);
    float s = 0.f;
    #pragma unroll
    for (int c = 0; c < 8; ++c) {              // chunk c: f16 elems 8c..8c+7
        float4 ea = e4[2 * c], eb = e4[2 * c + 1];
        s += ea.x * ea.x + ea.y * ea.y + ea.z * ea.z + ea.w * ea.w;   // R1-order
        s += eb.x * eb.x + eb.y * eb.y + eb.z * eb.z + eb.w * eb.w;
        float sc[8] = {ea.x * SCALE, ea.y * SCALE, ea.z * SCALE, ea.w * SCALE,
                       eb.x * SCALE, eb.y * SCALE, eb.z * SCALE, eb.w * SCALE};
        half8 hh, hl;
        #pragma unroll
        for (int e = 0; e < 8; ++e) {
            _Float16 h = (_Float16)sc[e];
            hh[e] = h;
            hl[e] = (_Float16)(sc[e] - (float)h);
        }
        const int kk = c >> 2, kg = c & 3;
        char* dst = tbase + kk * 8192 + ci * 1024 + (kg * 16 + frk) * 16;
        *(half8*)dst            = hh;          // eh (h=0)
        *(half8*)(dst + 16384)  = hl;          // el (h=1)
    }
    enorm[k]  = s;
    enorm2[k] = s * (SCALE * SCALE);           // pow2 mul: exact
}

// ------ MFMA filter: BARRIER-FREE, B frags direct from global (L1/L2) ------
// R21 vs R20 (passed, gemm ~47us, ~75% barrier/latency stall at a pinned
// 2 waves/SIMD): drop LDS staging + ALL per-tile __syncthreads. Bp is packed
// fragment-linear so each B-frag read is ONE coalesced global_load_dwordx4
// (per-lane 16B, 1KB/wave-instr; tile L1-resident, Bp L2-resident). Waves
// free-run; compiler pipelines the 32 independent loads/tile via vmcnt.
// Math/top-2/margin/epilogue verbatim from R20 (passed).
__global__ __launch_bounds__(256) void vq_gemm(const float* __restrict__ x,
                                               const char* __restrict__ Bp,
                                               const float* __restrict__ emb,
                                               const float* __restrict__ enorm2,
                                               float* __restrict__ out,
                                               unsigned* __restrict__ list,
                                               unsigned* __restrict__ counter,
                                               u64* __restrict__ errAcc) {
    __shared__ float redE[256];                // only LDS use (1 KB)

    const int tid  = threadIdx.x;
    const int lane = tid & 63, w = tid >> 6;
    const int fr   = lane & 15;                // frag row (A) / frag col (B)
    const int kg   = lane >> 4;                // k-group 0..3
    const int rb   = (int)blockIdx.x * BR;

    // ---- A fragments: direct global load + scale/split in registers ----
    const float4* x4 = (const float4*)x;
    half8 ah[2][2], al[2][2];
    #pragma unroll
    for (int fi = 0; fi < 2; ++fi) {
        #pragma unroll
        for (int kk = 0; kk < 2; ++kk) {
            int row = rb + w * 32 + fi * 16 + fr;
            float4 v0 = x4[(size_t)row * 16 + kk * 8 + kg * 2];
            float4 v1 = x4[(size_t)row * 16 + kk * 8 + kg * 2 + 1];
            float sc[8] = {v0.x * SCALE, v0.y * SCALE, v0.z * SCALE, v0.w * SCALE,
                           v1.x * SCALE, v1.y * SCALE, v1.z * SCALE, v1.w * SCALE};
            #pragma unroll
            for (int e = 0; e < 8; ++e) {
                _Float16 h = (_Float16)sc[e];
                ah[fi][kk][e] = h;
                al[fi][kk][e] = (_Float16)(sc[e] - (float)h);
            }
        }
    }

    // running top-2 state per (fi,rg): exact f32 dists + best idx
    float d1[2][4], d2[2][4];
    int   i1[2][4];
    #pragma unroll
    for (int fi = 0; fi < 2; ++fi)
        #pragma unroll
        for (int rg = 0; rg < 4; ++rg) {
            d1[fi][rg] = 3.4e38f; d2[fi][rg] = 3.4e38f; i1[fi][rg] = 0;
        }

    for (int ct = 0; ct < NCT; ++ct) {
        const int cb = ct * BC;
        const char* tb = Bp + (size_t)ct * 32768 + (size_t)lane * 16;

        float en2f[8];
        #pragma unroll
        for (int ci = 0; ci < 8; ++ci)         // per-lane, L1/L2-cached
            en2f[ci] = enorm2[cb + ci * 16 + fr];
        const int idxb = cb + fr;

        #pragma unroll
        for (int g = 0; g < 2; ++g) {          // ci-groups of 4 (caps VGPR)
            f32x4 acc[2][4];
            #pragma unroll
            for (int fi = 0; fi < 2; ++fi)
                #pragma unroll
                for (int i = 0; i < 4; ++i) acc[fi][i] = (f32x4){0.f, 0.f, 0.f, 0.f};

            #pragma unroll
            for (int kk = 0; kk < 2; ++kk) {
                const char* kb = tb + kk * 8192;
                half8 bf[4];
                #pragma unroll
                for (int i = 0; i < 4; ++i)    // bh frags: coalesced 1KB bursts
                    bf[i] = *(const half8*)(kb + (g * 4 + i) * 1024);
                #pragma unroll                 // 8 independent, then dependents at dist 8
                for (int fi = 0; fi < 2; ++fi)
                    #pragma unroll
                    for (int i = 0; i < 4; ++i)
                        acc[fi][i] = __builtin_amdgcn_mfma_f32_16x16x32_f16(ah[fi][kk], bf[i], acc[fi][i], 0, 0, 0);
                #pragma unroll
                for (int fi = 0; fi < 2; ++fi)
                    #pragma unroll
                    for (int i = 0; i < 4; ++i)
                        acc[fi][i] = __builtin_amdgcn_mfma_f32_16x16x32_f16(al[fi][kk], bf[i], acc[fi][i], 0, 0, 0);
                #pragma unroll
                for (int i = 0; i < 4; ++i)    // bl frags
                    bf[i] = *(const half8*)(kb + 16384 + (g * 4 + i) * 1024);
                #pragma unroll
                for (int fi = 0; fi < 2; ++fi)
                    #pragma unroll
                    for (int i = 0; i < 4; ++i)
                        acc[fi][i] = __builtin_amdgcn_mfma_f32_16x16x32_f16(ah[fi][kk], bf[i], acc[fi][i], 0, 0, 0);
            }

            // f32 streaming top-2 update (ci ascending; strict < tiebreak)
            #pragma unroll
            for (int fi = 0; fi < 2; ++fi) {
                #pragma unroll
                for (int rg = 0; rg < 4; ++rg) {
                    #pragma unroll
                    for (int i = 0; i < 4; ++i) {
                        float d  = fmaf(-2.f, acc[fi][i][rg], en2f[g * 4 + i]);
                        int  idx = idxb + (g * 4 + i) * 16;
                        bool lt  = d < d1[fi][rg];
                        d2[fi][rg] = fminf(fmaxf(d1[fi][rg], d), d2[fi][rg]);
                        i1[fi][rg] = lt ? idx : i1[fi][rg];
                        d1[fi][rg] = fminf(d1[fi][rg], d);
                    }
                }
            }
        }
    }

    // ---- fused epilogue: butterfly, margin test, output write, err accum --
    const float4* e4g = (const float4*)emb;
    float4* o4 = (float4*)out;
    float errp = 0.f;
    #pragma unroll
    for (int fi = 0; fi < 2; ++fi) {
        #pragma unroll
        for (int rg = 0; rg < 4; ++rg) {
            float v1 = d1[fi][rg], v2 = d2[fi][rg];
            int   ii = i1[fi][rg];
            #pragma unroll
            for (int off = 8; off >= 1; off >>= 1) {
                float o1 = __shfl_xor(v1, off, 16);
                float o2 = __shfl_xor(v2, off, 16);
                int   oi = __shfl_xor(ii, off, 16);
                float loser = fmaxf(v1, o1);
                v2 = fminf(fminf(v2, o2), loser);
                bool bt = o1 < v1;              // exact tie -> margin fails anyway
                v1 = fminf(v1, o1);
                ii = bt ? oi : ii;
            }
            int row = rb + w * 32 + fi * 16 + kg * 4 + rg;
            if (v2 - v1 > THR) {                // provably ref argmin: write output
                float4 q = e4g[(size_t)ii * 16 + fr];
                float4 v = x4[(size_t)row * 16 + fr];
                o4[(size_t)row * 16 + fr] = q;
                float ax = q.x - v.x, ay = q.y - v.y, az = q.z - v.z, aw = q.w - v.w;
                errp += ax * ax + ay * ay + az * az + aw * aw;
            } else if (fr == 0) {
                unsigned pos = atomicAdd(counter, 1u);
                list[pos] = (unsigned)row;      // fallback writes out + err
            }
        }
    }

    // deterministic block err reduce -> one fixed-point atomic
    __syncthreads();
    redE[tid] = errp;
    __syncthreads();
    for (int s = 128; s > 0; s >>= 1) {
        if (tid < s) redE[tid] += redE[tid + s];
        __syncthreads();
    }
    if (tid == 0)
        atomicAdd(errAcc, (u64)((double)redE[0] * FXS + 0.5));
}

// ---------- exact fallback: full 1024-code scan, R1 form; writes out + err --
__global__ __launch_bounds__(256) void vq_fallback(const float* __restrict__ x,
                                                   const float* __restrict__ emb,
                                                   const float* __restrict__ enorm,
                                                   const unsigned* __restrict__ list,
                                                   const unsigned* __restrict__ counter,
                                                   float* __restrict__ out,
                                                   u64* __restrict__ errAcc) {
    __shared__ float4 xr[16];
    __shared__ u64 red[256];
    __shared__ float errv[16];
    const int tid = threadIdx.x;
    const unsigned total = counter[0];
    u64 qerr = 0ull;
    for (unsigned i = blockIdx.x; i < total; i += gridDim.x) {
        const int n = (int)list[i];
        __syncthreads();
        if (tid < 16) xr[tid] = ((const float4*)x)[(size_t)n * 16 + tid];
        __syncthreads();
        float xnorm = 0.f;                     // R1-order xnorm
        #pragma unroll
        for (int q = 0; q < 16; ++q) {
            float4 v = xr[q];
            xnorm += v.x * v.x + v.y * v.y + v.z * v.z + v.w * v.w;
        }
        u64 best = ~0ull;
        #pragma unroll
        for (int j = 0; j < 4; ++j) {
            int k = tid + j * 256;
            const float4* e4 = (const float4*)(emb + (size_t)k * D);
            float d0 = 0.f, d1v = 0.f, d2v = 0.f, d3v = 0.f;
            #pragma unroll
            for (int q = 0; q < 4; ++q) {      // proven R1 4-chain ordering
                float4 ea = e4[q*4+0], eb = e4[q*4+1], ec = e4[q*4+2], ed = e4[q*4+3];
                float4 va = xr[q*4+0], vb = xr[q*4+1], vc = xr[q*4+2], vd = xr[q*4+3];
                d0  = fmaf(va.w, ea.w, fmaf(va.z, ea.z, fmaf(va.y, ea.y, fmaf(va.x, ea.x, d0))));
                d1v = fmaf(vb.w, eb.w, fmaf(vb.z, eb.z, fmaf(vb.y, eb.y, fmaf(vb.x, eb.x, d1v))));
                d2v = fmaf(vc.w, ec.w, fmaf(vc.z, ec.z, fmaf(vc.y, ec.y, fmaf(vc.x, ec.x, d2v))));
                d3v = fmaf(vd.w, ed.w, fmaf(vd.z, ed.z, fmaf(vd.y, ed.y, fmaf(vd.x, ed.x, d3v))));
            }
            float dot  = (d0 + d1v) + (d2v + d3v);
            float dist = fmaf(-2.f, dot, xnorm + enorm[k]);
            u64 pk = ((u64)ordf(dist) << 32) | (unsigned)k;
            if (pk < best) best = pk;          // dist-then-lowest-idx
        }
        red[tid] = best;
        __syncthreads();
        for (int s = 128; s > 0; s >>= 1) {
            if (tid < s) red[tid] = red[tid] < red[tid+s] ? red[tid] : red[tid+s];
            __syncthreads();
        }
        const int bi = (int)(red[0] & 0xFFFFFFFFu);
        if (tid < 16) {                        // write output + per-lane err
            float4 q = ((const float4*)emb)[(size_t)bi * 16 + tid];
            float4 v = xr[tid];
            ((float4*)out)[(size_t)n * 16 + tid] = q;
            float ax = q.x - v.x, ay = q.y - v.y, az = q.z - v.z, aw = q.w - v.w;
            errv[tid] = ax * ax + ay * ay + az * az + aw * aw;
        }
        __syncthreads();
        if (tid == 0) {                        // deterministic fixed-order sum
            float re = 0.f;
            #pragma unroll
            for (int j = 0; j < 16; ++j) re += errv[j];
            qerr += (u64)((double)re * FXS + 0.5);
        }
    }
    if (tid == 0 && qerr) atomicAdd(errAcc, qerr);
}

// ------------------------------------------------------------- finalize ----
__global__ __launch_bounds__(64) void vq_finish(const u64* __restrict__ errAcc,
                                                float* __restrict__ loss_out) {
    if (threadIdx.x == 0) {
        double s = (double)errAcc[0] / FXS;
        loss_out[0] = (float)((1.0 + (double)BETA) * s / (double)((size_t)NROWS * D));
    }
}

// ---------------------------------------------------------------- launch ---
extern "C" void kernel_launch(void* const* d_in, const int* in_sizes, int n_in,
                              void* d_out, int out_size, void* d_ws, size_t ws_size,
                              hipStream_t stream) {
    const float* x   = (const float*)d_in[0];
    const float* emb = (const float*)d_in[1];
    float* out = (float*)d_out;
    char* ws = (char*)d_ws;

    char* Bp          = ws + WS_BP;
    float* enorm      = (float*)(ws + WS_EN);
    float* enorm2     = (float*)(ws + WS_EN2);
    unsigned* list    = (unsigned*)(ws + WS_LIST);
    unsigned* counter = (unsigned*)(ws + WS_CNT);
    u64* errAcc       = (u64*)(ws + WS_ERR);

    vq_prep<<<K / 256, 256, 0, stream>>>(emb, enorm, enorm2, Bp, counter, errAcc);
    vq_gemm<<<NROWS / BR, 256, 0, stream>>>(x, Bp, emb, enorm2, out, list, counter, errAcc);
    vq_fallback<<<128, 256, 0, stream>>>(x, emb, enorm, list, counter, out, errAcc);
    vq_finish<<<1, 64, 0, stream>>>(errAcc, out + (size_t)NROWS * D);
}

// Round 22
// 76.840 us; speedup vs baseline: 1.0058x; 1.0058x over previous
//
#include <hip/hip_runtime.h>
#include <math.h>

#define NROWS 65536
#define D     64
#define K     1024
#define NCT   8            // code tiles (K/128)
#define BR    128
#define BC    128
#define BETA  0.25f
#define SCALE 1024.0f      // pow2 -> exact f32 scaling; keeps xl/el f16-normal
#define THR   200.0f       // scaled-dist margin (R15-proven)
#define FXS   1048576.0    // fixed-point scale 2^20 for deterministic loss sum

typedef _Float16 half8  __attribute__((ext_vector_type(8)));
typedef float    f32x4  __attribute__((ext_vector_type(4)));
typedef unsigned long long u64;

// ws layout (bytes)
// Bp fragment-linear: [ct:32768][h:16384][kk:8192][ci:1024][lane:16]
//   lane = kg*16 + fr holds f16 elems [kk*32+kg*8, +8) of code ct*128+ci*16+fr
#define WS_BP   0u                         // 256 KB
#define WS_EN   (256u*1024)                // f32 [K] enorm (4 KB)
#define WS_EN2  (260u*1024)                // f32 [K] enorm*S^2 (4 KB)
#define WS_LIST (264u*1024)                // u32 [NROWS] (256 KB)
#define WS_CNT  (WS_LIST + 256u*1024)      // u32 counter (pad 128)
#define WS_ERR  (WS_CNT + 128u)            // u64 fixed-point err accumulator

static __device__ __forceinline__ unsigned ordf(float f) {
    unsigned b = __float_as_uint(f);
    return (b & 0x80000000u) ? ~b : (b | 0x80000000u);
}

// ------------------- prep: enorm + fragment-linear packed B + accum resets --
__global__ __launch_bounds__(256) void vq_prep(const float* __restrict__ emb,
                                               float* __restrict__ enorm,
                                               float* __restrict__ enorm2,
                                               char* __restrict__ Bp,
                                               unsigned* __restrict__ counter,
                                               u64* __restrict__ errAcc) {
    if (blockIdx.x == 0 && threadIdx.x == 0) { counter[0] = 0u; errAcc[0] = 0ull; }
    int k = blockIdx.x * 256 + threadIdx.x;
    if (k >= K) return;
    const int ct  = k >> 7;
    const int ci  = (k & 127) >> 4;
    const int frk = k & 15;
    char* tbase = Bp + (size_t)ct * 32768;
    const float4* e4 = (const float4*)(emb + (size_t)k * D);
    float s = 0.f;
    #pragma unroll
    for (int c = 0; c < 8; ++c) {              // chunk c: f16 elems 8c..8c+7
        float4 ea = e4[2 * c], eb = e4[2 * c + 1];
        s += ea.x * ea.x + ea.y * ea.y + ea.z * ea.z + ea.w * ea.w;   // R1-order
        s += eb.x * eb.x + eb.y * eb.y + eb.z * eb.z + eb.w * eb.w;
        float sc[8] = {ea.x * SCALE, ea.y * SCALE, ea.z * SCALE, ea.w * SCALE,
                       eb.x * SCALE, eb.y * SCALE, eb.z * SCALE, eb.w * SCALE};
        half8 hh, hl;
        #pragma unroll
        for (int e = 0; e < 8; ++e) {
            _Float16 h = (_Float16)sc[e];
            hh[e] = h;
            hl[e] = (_Float16)(sc[e] - (float)h);
        }
        const int kk = c >> 2, kg = c & 3;
        char* dst = tbase + kk * 8192 + ci * 1024 + (kg * 16 + frk) * 16;
        *(half8*)dst            = hh;          // eh (h=0)
        *(half8*)(dst + 16384)  = hl;          // el (h=1)
    }
    enorm[k]  = s;
    enorm2[k] = s * (SCALE * SCALE);           // pow2 mul: exact
}

// ------ MFMA filter: BARRIER-FREE, B frags direct from global (L1/L2) ------
// R21 vs R20 (passed, gemm ~47us, ~75% barrier/latency stall at a pinned
// 2 waves/SIMD): drop LDS staging + ALL per-tile __syncthreads. Bp is packed
// fragment-linear so each B-frag read is ONE coalesced global_load_dwordx4
// (per-lane 16B, 1KB/wave-instr; tile L1-resident, Bp L2-resident). Waves
// free-run; compiler pipelines the 32 independent loads/tile via vmcnt.
// Math/top-2/margin/epilogue verbatim from R20 (passed).
__global__ __launch_bounds__(256) void vq_gemm(const float* __restrict__ x,
                                               const char* __restrict__ Bp,
                                               const float* __restrict__ emb,
                                               const float* __restrict__ enorm2,
                                               float* __restrict__ out,
                                               unsigned* __restrict__ list,
                                               unsigned* __restrict__ counter,
                                               u64* __restrict__ errAcc) {
    __shared__ float redE[256];                // only LDS use (1 KB)

    const int tid  = threadIdx.x;
    const int lane = tid & 63, w = tid >> 6;
    const int fr   = lane & 15;                // frag row (A) / frag col (B)
    const int kg   = lane >> 4;                // k-group 0..3
    const int rb   = (int)blockIdx.x * BR;

    // ---- A fragments: direct global load + scale/split in registers ----
    const float4* x4 = (const float4*)x;
    half8 ah[2][2], al[2][2];
    #pragma unroll
    for (int fi = 0; fi < 2; ++fi) {
        #pragma unroll
        for (int kk = 0; kk < 2; ++kk) {
            int row = rb + w * 32 + fi * 16 + fr;
            float4 v0 = x4[(size_t)row * 16 + kk * 8 + kg * 2];
            float4 v1 = x4[(size_t)row * 16 + kk * 8 + kg * 2 + 1];
            float sc[8] = {v0.x * SCALE, v0.y * SCALE, v0.z * SCALE, v0.w * SCALE,
                           v1.x * SCALE, v1.y * SCALE, v1.z * SCALE, v1.w * SCALE};
            #pragma unroll
            for (int e = 0; e < 8; ++e) {
                _Float16 h = (_Float16)sc[e];
                ah[fi][kk][e] = h;
                al[fi][kk][e] = (_Float16)(sc[e] - (float)h);
            }
        }
    }

    // running top-2 state per (fi,rg): exact f32 dists + best idx
    float d1[2][4], d2[2][4];
    int   i1[2][4];
    #pragma unroll
    for (int fi = 0; fi < 2; ++fi)
        #pragma unroll
        for (int rg = 0; rg < 4; ++rg) {
            d1[fi][rg] = 3.4e38f; d2[fi][rg] = 3.4e38f; i1[fi][rg] = 0;
        }

    for (int ct = 0; ct < NCT; ++ct) {
        const int cb = ct * BC;
        const char* tb = Bp + (size_t)ct * 32768 + (size_t)lane * 16;

        float en2f[8];
        #pragma unroll
        for (int ci = 0; ci < 8; ++ci)         // per-lane, L1/L2-cached
            en2f[ci] = enorm2[cb + ci * 16 + fr];
        const int idxb = cb + fr;

        #pragma unroll
        for (int g = 0; g < 2; ++g) {          // ci-groups of 4 (caps VGPR)
            f32x4 acc[2][4];
            #pragma unroll
            for (int fi = 0; fi < 2; ++fi)
                #pragma unroll
                for (int i = 0; i < 4; ++i) acc[fi][i] = (f32x4){0.f, 0.f, 0.f, 0.f};

            #pragma unroll
            for (int kk = 0; kk < 2; ++kk) {
                const char* kb = tb + kk * 8192;
                half8 bf[4];
                #pragma unroll
                for (int i = 0; i < 4; ++i)    // bh frags: coalesced 1KB bursts
                    bf[i] = *(const half8*)(kb + (g * 4 + i) * 1024);
                #pragma unroll                 // 8 independent, then dependents at dist 8
                for (int fi = 0; fi < 2; ++fi)
                    #pragma unroll
                    for (int i = 0; i < 4; ++i)
                        acc[fi][i] = __builtin_amdgcn_mfma_f32_16x16x32_f16(ah[fi][kk], bf[i], acc[fi][i], 0, 0, 0);
                #pragma unroll
                for (int fi = 0; fi < 2; ++fi)
                    #pragma unroll
                    for (int i = 0; i < 4; ++i)
                        acc[fi][i] = __builtin_amdgcn_mfma_f32_16x16x32_f16(al[fi][kk], bf[i], acc[fi][i], 0, 0, 0);
                #pragma unroll
                for (int i = 0; i < 4; ++i)    // bl frags
                    bf[i] = *(const half8*)(kb + 16384 + (g * 4 + i) * 1024);
                #pragma unroll
                for (int fi = 0; fi < 2; ++fi)
                    #pragma unroll
                    for (int i = 0; i < 4; ++i)
                        acc[fi][i] = __builtin_amdgcn_mfma_f32_16x16x32_f16(ah[fi][kk], bf[i], acc[fi][i], 0, 0, 0);
            }

            // f32 streaming top-2 update (ci ascending; strict < tiebreak)
            #pragma unroll
            for (int fi = 0; fi < 2; ++fi) {
                #pragma unroll
                for (int rg = 0; rg < 4; ++rg) {
                    #pragma unroll
                    for (int i = 0; i < 4; ++i) {
                        float d  = fmaf(-2.f, acc[fi][i][rg], en2f[g * 4 + i]);
                        int  idx = idxb + (g * 4 + i) * 16;
                        bool lt  = d < d1[fi][rg];
                        d2[fi][rg] = fminf(fmaxf(d1[fi][rg], d), d2[fi][rg]);
                        i1[fi][rg] = lt ? idx : i1[fi][rg];
                        d1[fi][rg] = fminf(d1[fi][rg], d);
                    }
                }
            }
        }
    }

    // ---- fused epilogue: butterfly, margin test, output write, err accum --
    const float4* e4g = (const float4*)emb;
    float4* o4 = (float4*)out;
    float errp = 0.f;
    #pragma unroll
    for (int fi = 0; fi < 2; ++fi) {
        #pragma unroll
        for (int rg = 0; rg < 4; ++rg) {
            float v1 = d1[fi][rg], v2 = d2[fi][rg];
            int   ii = i1[fi][rg];
            #pragma unroll
            for (int off = 8; off >= 1; off >>= 1) {
                float o1 = __shfl_xor(v1, off, 16);
                float o2 = __shfl_xor(v2, off, 16);
                int   oi = __shfl_xor(ii, off, 16);
                float loser = fmaxf(v1, o1);
                v2 = fminf(fminf(v2, o2), loser);
                bool bt = o1 < v1;              // exact tie -> margin fails anyway
                v1 = fminf(v1, o1);
                ii = bt ? oi : ii;
            }
            int row = rb + w * 32 + fi * 16 + kg * 4 + rg;
            if (v2 - v1 > THR) {                // provably ref argmin: write output
                float4 q = e4g[(size_t)ii * 16 + fr];
                float4 v = x4[(size_t)row * 16 + fr];
                o4[(size_t)row * 16 + fr] = q;
                float ax = q.x - v.x, ay = q.y - v.y, az = q.z - v.z, aw = q.w - v.w;
                errp += ax * ax + ay * ay + az * az + aw * aw;
            } else if (fr == 0) {
                unsigned pos = atomicAdd(counter, 1u);
                list[pos] = (unsigned)row;      // fallback writes out + err
            }
        }
    }

    // deterministic block err reduce -> one fixed-point atomic
    __syncthreads();
    redE[tid] = errp;
    __syncthreads();
    for (int s = 128; s > 0; s >>= 1) {
        if (tid < s) redE[tid] += redE[tid + s];
        __syncthreads();
    }
    if (tid == 0)
        atomicAdd(errAcc, (u64)((double)redE[0] * FXS + 0.5));
}

// ---------- exact fallback: full 1024-code scan, R1 form; writes out + err --
__global__ __launch_bounds__(256) void vq_fallback(const float* __restrict__ x,
                                                   const float* __restrict__ emb,
                                                   const float* __restrict__ enorm,
                                                   const unsigned* __restrict__ list,
                                                   const unsigned* __restrict__ counter,
                                                   float* __restrict__ out,
                                                   u64* __restrict__ errAcc) {
    __shared__ float4 xr[16];
    __shared__ u64 red[256];
    __shared__ float errv[16];
    const int tid = threadIdx.x;
    const unsigned total = counter[0];
    u64 qerr = 0ull;
    for (unsigned i = blockIdx.x; i < total; i += gridDim.x) {
        const int n = (int)list[i];
        __syncthreads();
        if (tid < 16) xr[tid] = ((const float4*)x)[(size_t)n * 16 + tid];
        __syncthreads();
        float xnorm = 0.f;                     // R1-order xnorm
        #pragma unroll
        for (int q = 0; q < 16; ++q) {
            float4 v = xr[q];
            xnorm += v.x * v.x + v.y * v.y + v.z * v.z + v.w * v.w;
        }
        u64 best = ~0ull;
        #pragma unroll
        for (int j = 0; j < 4; ++j) {
            int k = tid + j * 256;
            const float4* e4 = (const float4*)(emb + (size_t)k * D);
            float d0 = 0.f, d1v = 0.f, d2v = 0.f, d3v = 0.f;
            #pragma unroll
            for (int q = 0; q < 4; ++q) {      // proven R1 4-chain ordering
                float4 ea = e4[q*4+0], eb = e4[q*4+1], ec = e4[q*4+2], ed = e4[q*4+3];
                float4 va = xr[q*4+0], vb = xr[q*4+1], vc = xr[q*4+2], vd = xr[q*4+3];
                d0  = fmaf(va.w, ea.w, fmaf(va.z, ea.z, fmaf(va.y, ea.y, fmaf(va.x, ea.x, d0))));
                d1v = fmaf(vb.w, eb.w, fmaf(vb.z, eb.z, fmaf(vb.y, eb.y, fmaf(vb.x, eb.x, d1v))));
                d2v = fmaf(vc.w, ec.w, fmaf(vc.z, ec.z, fmaf(vc.y, ec.y, fmaf(vc.x, ec.x, d2v))));
                d3v = fmaf(vd.w, ed.w, fmaf(vd.z, ed.z, fmaf(vd.y, ed.y, fmaf(vd.x, ed.x, d3v))));
            }
            float dot  = (d0 + d1v) + (d2v + d3v);
            float dist = fmaf(-2.f, dot, xnorm + enorm[k]);
            u64 pk = ((u64)ordf(dist) << 32) | (unsigned)k;
            if (pk < best) best = pk;          // dist-then-lowest-idx
        }
        red[tid] = best;
        __syncthreads();
        for (int s = 128; s > 0; s >>= 1) {
            if (tid < s) red[tid] = red[tid] < red[tid+s] ? red[tid] : red[tid+s];
            __syncthreads();
        }
        const int bi = (int)(red[0] & 0xFFFFFFFFu);
        if (tid < 16) {                        // write output + per-lane err
            float4 q = ((const float4*)emb)[(size_t)bi * 16 + tid];
            float4 v = xr[tid];
            ((float4*)out)[(size_t)n * 16 + tid] = q;
            float ax = q.x - v.x, ay = q.y - v.y, az = q.z - v.z, aw = q.w - v.w;
            errv[tid] = ax * ax + ay * ay + az * az + aw * aw;
        }
        __syncthreads();
        if (tid == 0) {                        // deterministic fixed-order sum
            float re = 0.f;
            #pragma unroll
            for (int j = 0; j < 16; ++j) re += errv[j];
            qerr += (u64)((double)re * FXS + 0.5);
        }
    }
    if (tid == 0 && qerr) atomicAdd(errAcc, qerr);
}

// ------------------------------------------------------------- finalize ----
__global__ __launch_bounds__(64) void vq_finish(const u64* __restrict__ errAcc,
                                                float* __restrict__ loss_out) {
    if (threadIdx.x == 0) {
        double s = (double)errAcc[0] / FXS;
        loss_out[0] = (float)((1.0 + (double)BETA) * s / (double)((size_t)NROWS * D));
    }
}

// ---------------------------------------------------------------- launch ---
extern "C" void kernel_launch(void* const* d_in, const int* in_sizes, int n_in,
                              void* d_out, int out_size, void* d_ws, size_t ws_size,
                              hipStream_t stream) {
    const float* x   = (const float*)d_in[0];
    const float* emb = (const float*)d_in[1];
    float* out = (float*)d_out;
    char* ws = (char*)d_ws;

    char* Bp          = ws + WS_BP;
    float* enorm      = (float*)(ws + WS_EN);
    float* enorm2     = (float*)(ws + WS_EN2);
    unsigned* list    = (unsigned*)(ws + WS_LIST);
    unsigned* counter = (unsigned*)(ws + WS_CNT);
    u64* errAcc       = (u64*)(ws + WS_ERR);

    vq_prep<<<K / 256, 256, 0, stream>>>(emb, enorm, enorm2, Bp, counter, errAcc);
    vq_gemm<<<NROWS / BR, 256, 0, stream>>>(x, Bp, emb, enorm2, out, list, counter, errAcc);
    vq_fallback<<<128, 256, 0, stream>>>(x, emb, enorm, list, counter, out, errAcc);
    vq_finish<<<1, 64, 0, stream>>>(errAcc, out + (size_t)NROWS * D);
}

// Round 23
// 61.738 us; speedup vs baseline: 1.2519x; 1.2446x over previous
//
#include <hip/hip_runtime.h>
#include <math.h>

#define NROWS 65536
#define D     64
#define K     1024
#define NCT   8            // code tiles (K/128)
#define BR    128
#define BC    128
#define BETA  0.25f
#define SCALE 1024.0f      // pow2 -> exact f32 scaling; keeps xl/el f16-normal
#define THR   200.0f       // scaled-dist margin (R15-proven)
#define FXS   1048576.0    // fixed-point scale 2^20 for deterministic loss sum

typedef _Float16 half8  __attribute__((ext_vector_type(8)));
typedef float    f32x4  __attribute__((ext_vector_type(4)));
typedef unsigned long long u64;

// ws layout (bytes)
#define WS_BP   0u                         // 8 tiles x 32 KB = 256 KB (LDS image, swizzled)
#define WS_EN   (256u*1024)                // f32 [K] enorm (4 KB)
#define WS_EN2  (260u*1024)                // f32 [K] enorm*S^2 (4 KB)
#define WS_LIST (264u*1024)                // u32 [NROWS] (256 KB)
#define WS_CNT  (WS_LIST + 256u*1024)      // u32 counter (pad 128)
#define WS_ERR  (WS_CNT + 128u)            // u64 fixed-point err accumulator

static __device__ __forceinline__ unsigned ordf(float f) {
    unsigned b = __float_as_uint(f);
    return (b & 0x80000000u) ? ~b : (b | 0x80000000u);
}
static __device__ __forceinline__ void gload_lds16(const void* g, void* l) {
    __builtin_amdgcn_global_load_lds(
        (const __attribute__((address_space(1))) unsigned*)g,
        (__attribute__((address_space(3))) unsigned*)l,
        16, 0, 0);
}

// ------------------- prep: enorm + swizzled/tiled packed B + accum resets --
__global__ __launch_bounds__(256) void vq_prep(const float* __restrict__ emb,
                                               float* __restrict__ enorm,
                                               float* __restrict__ enorm2,
                                               char* __restrict__ Bp,
                                               unsigned* __restrict__ counter,
                                               u64* __restrict__ errAcc) {
    if (blockIdx.x == 0 && threadIdx.x == 0) { counter[0] = 0u; errAcc[0] = 0ull; }
    int k = blockIdx.x * 256 + threadIdx.x;
    if (k >= K) return;
    const int ct = k >> 7, r = k & 127;
    char* base = Bp + (size_t)ct * 32768 + (size_t)r * 128;
    const float4* e4 = (const float4*)(emb + (size_t)k * D);
    float s = 0.f;
    #pragma unroll
    for (int c = 0; c < 8; ++c) {              // chunk c = f16 elems 8c..8c+7
        float4 ea = e4[2 * c], eb = e4[2 * c + 1];
        s += ea.x * ea.x + ea.y * ea.y + ea.z * ea.z + ea.w * ea.w;   // R1-order
        s += eb.x * eb.x + eb.y * eb.y + eb.z * eb.z + eb.w * eb.w;
        float sc[8] = {ea.x * SCALE, ea.y * SCALE, ea.z * SCALE, ea.w * SCALE,
                       eb.x * SCALE, eb.y * SCALE, eb.z * SCALE, eb.w * SCALE};
        half8 hh, hl;
        #pragma unroll
        for (int e = 0; e < 8; ++e) {
            _Float16 h = (_Float16)sc[e];
            hh[e] = h;
            hl[e] = (_Float16)(sc[e] - (float)h);
        }
        int off = ((c ^ (r & 7)) << 4);
        *(half8*)(base + off)         = hh;     // eh
        *(half8*)(base + 16384 + off) = hl;     // el
    }
    enorm[k]  = s;
    enorm2[k] = s * (SCALE * SCALE);           // pow2 mul: exact
}

// --------------- MFMA filter (R20-proven) + counted-vmcnt barrier pipeline --
// R23 vs R20 (passed, gemm ~47us): replace per-tile __syncthreads (whose
// implicit vmcnt(0) drain gated all waves 8x/block) with raw s_barrier pairs
// + explicit s_waitcnt vmcnt(8): after issuing tile ct+1's 8 gload_lds,
// vmcnt(8) retires exactly tile ct's loads (FIFO, m135) while ct+1's stay in
// flight across the barriers and land under ct's compute (m139-validated
// pattern). Prereq: NO other in-loop vmem -> enorm2 staged to LDS in
// prologue. Math/top-2/margin/epilogue/fallback verbatim R20.
__global__ __launch_bounds__(256, 2) void vq_gemm(const float* __restrict__ x,
                                                  const char* __restrict__ Bp,
                                                  const float* __restrict__ emb,
                                                  const float* __restrict__ enorm2,
                                                  float* __restrict__ out,
                                                  unsigned* __restrict__ list,
                                                  unsigned* __restrict__ counter,
                                                  u64* __restrict__ errAcc) {
    __shared__ __align__(16) char bufB[2][32768];   // 64 KB double buffer
    __shared__ float lds_en2[K];                    // 4 KB
    __shared__ float redE[256];                     // 1 KB

    const int tid  = threadIdx.x;
    const int lane = tid & 63, w = tid >> 6;
    const int fr   = lane & 15;                // frag row (A) / frag col (B)
    const int kg   = lane >> 4;                // k-group 0..3
    const int rb   = (int)blockIdx.x * BR;

    // ---- A fragments: direct global load + scale/split in registers ----
    const float4* x4 = (const float4*)x;
    half8 ah[2][2], al[2][2];
    #pragma unroll
    for (int fi = 0; fi < 2; ++fi) {
        #pragma unroll
        for (int kk = 0; kk < 2; ++kk) {
            int row = rb + w * 32 + fi * 16 + fr;
            float4 v0 = x4[(size_t)row * 16 + kk * 8 + kg * 2];
            float4 v1 = x4[(size_t)row * 16 + kk * 8 + kg * 2 + 1];
            float sc[8] = {v0.x * SCALE, v0.y * SCALE, v0.z * SCALE, v0.w * SCALE,
                           v1.x * SCALE, v1.y * SCALE, v1.z * SCALE, v1.w * SCALE};
            #pragma unroll
            for (int e = 0; e < 8; ++e) {
                _Float16 h = (_Float16)sc[e];
                ah[fi][kk][e] = h;
                al[fi][kk][e] = (_Float16)(sc[e] - (float)h);
            }
        }
    }

    // ---- prologue: stage enorm2 to LDS (only vmem before loop), drain ----
    lds_en2[tid]       = enorm2[tid];
    lds_en2[tid + 256] = enorm2[tid + 256];
    lds_en2[tid + 512] = enorm2[tid + 512];
    lds_en2[tid + 768] = enorm2[tid + 768];
    __syncthreads();                           // full drain: nothing else in flight

    // ---- issue prefetch of B tile 0 (8 gload_lds / wave) ----
    {
        const char* gsrc = Bp + (size_t)w * 8192 + (size_t)lane * 16;
        char* ldst = &bufB[0][w * 8192];
        #pragma unroll
        for (int j = 0; j < 8; ++j)
            gload_lds16(gsrc + j * 1024, ldst + j * 1024);
    }

    // running top-2 state per (fi,rg): exact f32 dists + best idx
    float d1[2][4], d2[2][4];
    int   i1[2][4];
    #pragma unroll
    for (int fi = 0; fi < 2; ++fi)
        #pragma unroll
        for (int rg = 0; rg < 4; ++rg) {
            d1[fi][rg] = 3.4e38f; d2[fi][rg] = 3.4e38f; i1[fi][rg] = 0;
        }

    for (int ct = 0; ct < NCT; ++ct) {
        const int  cb  = ct * BC;
        const int  buf = ct & 1;

        // barrier #1: all waves done READING buf^1 (tile ct-1) -> safe to write
        __builtin_amdgcn_s_barrier();
        if (ct < NCT - 1) {                    // issue prefetch ct+1 -> buf^1
            const char* gsrc = Bp + (size_t)(ct + 1) * 32768 + (size_t)w * 8192
                             + (size_t)lane * 16;
            char* ldst = &bufB[buf ^ 1][w * 8192];
            #pragma unroll
            for (int j = 0; j < 8; ++j)
                gload_lds16(gsrc + j * 1024, ldst + j * 1024);
            // wait ONLY tile ct's 8 loads (oldest); ct+1's 8 stay in flight
            asm volatile("s_waitcnt vmcnt(8)" ::: "memory");
        } else {
            asm volatile("s_waitcnt vmcnt(0)" ::: "memory");
        }
        // barrier #2: every wave's tile-ct data has landed
        __builtin_amdgcn_s_barrier();
        __builtin_amdgcn_sched_barrier(0);     // fence: no hoisting of ds_reads

        float en2f[8];
        #pragma unroll
        for (int ci = 0; ci < 8; ++ci)         // LDS broadcast reads (lgkmcnt)
            en2f[ci] = lds_en2[cb + ci * 16 + fr];
        const int idxb = cb + fr;

        const char* bb = &bufB[buf][0];

        #pragma unroll
        for (int g = 0; g < 2; ++g) {          // ci-groups of 4 (caps VGPR)
            f32x4 acc[2][4];
            #pragma unroll
            for (int fi = 0; fi < 2; ++fi)
                #pragma unroll
                for (int i = 0; i < 4; ++i) acc[fi][i] = (f32x4){0.f, 0.f, 0.f, 0.f};

            #pragma unroll
            for (int kk = 0; kk < 2; ++kk) {
                const int chunk = ((kk * 4 + kg) ^ (fr & 7)) << 4;
                half8 bf[4];
                #pragma unroll
                for (int i = 0; i < 4; ++i)    // bh frags (swizzled, conflict-free)
                    bf[i] = *(const half8*)(bb + ((g * 4 + i) * 16 + fr) * 128 + chunk);
                #pragma unroll                 // 8 independent, then dependents at dist 8
                for (int fi = 0; fi < 2; ++fi)
                    #pragma unroll
                    for (int i = 0; i < 4; ++i)
                        acc[fi][i] = __builtin_amdgcn_mfma_f32_16x16x32_f16(ah[fi][kk], bf[i], acc[fi][i], 0, 0, 0);
                #pragma unroll
                for (int fi = 0; fi < 2; ++fi)
                    #pragma unroll
                    for (int i = 0; i < 4; ++i)
                        acc[fi][i] = __builtin_amdgcn_mfma_f32_16x16x32_f16(al[fi][kk], bf[i], acc[fi][i], 0, 0, 0);
                #pragma unroll
                for (int i = 0; i < 4; ++i)    // bl frags
                    bf[i] = *(const half8*)(bb + 16384 + ((g * 4 + i) * 16 + fr) * 128 + chunk);
                #pragma unroll
                for (int fi = 0; fi < 2; ++fi)
                    #pragma unroll
                    for (int i = 0; i < 4; ++i)
                        acc[fi][i] = __builtin_amdgcn_mfma_f32_16x16x32_f16(ah[fi][kk], bf[i], acc[fi][i], 0, 0, 0);
            }

            // f32 streaming top-2 update (ci ascending; strict < tiebreak)
            #pragma unroll
            for (int fi = 0; fi < 2; ++fi) {
                #pragma unroll
                for (int rg = 0; rg < 4; ++rg) {
                    #pragma unroll
                    for (int i = 0; i < 4; ++i) {
                        float d  = fmaf(-2.f, acc[fi][i][rg], en2f[g * 4 + i]);
                        int  idx = idxb + (g * 4 + i) * 16;
                        bool lt  = d < d1[fi][rg];
                        d2[fi][rg] = fminf(fmaxf(d1[fi][rg], d), d2[fi][rg]);
                        i1[fi][rg] = lt ? idx : i1[fi][rg];
                        d1[fi][rg] = fminf(d1[fi][rg], d);
                    }
                }
            }
        }
    }

    // ---- fused epilogue: butterfly, margin test, output write, err accum --
    const float4* e4g = (const float4*)emb;
    float4* o4 = (float4*)out;
    float errp = 0.f;
    #pragma unroll
    for (int fi = 0; fi < 2; ++fi) {
        #pragma unroll
        for (int rg = 0; rg < 4; ++rg) {
            float v1 = d1[fi][rg], v2 = d2[fi][rg];
            int   ii = i1[fi][rg];
            #pragma unroll
            for (int off = 8; off >= 1; off >>= 1) {
                float o1 = __shfl_xor(v1, off, 16);
                float o2 = __shfl_xor(v2, off, 16);
                int   oi = __shfl_xor(ii, off, 16);
                float loser = fmaxf(v1, o1);
                v2 = fminf(fminf(v2, o2), loser);
                bool bt = o1 < v1;              // exact tie -> margin fails anyway
                v1 = fminf(v1, o1);
                ii = bt ? oi : ii;
            }
            int row = rb + w * 32 + fi * 16 + kg * 4 + rg;
            if (v2 - v1 > THR) {                // provably ref argmin: write output
                float4 q = e4g[(size_t)ii * 16 + fr];
                float4 v = x4[(size_t)row * 16 + fr];
                o4[(size_t)row * 16 + fr] = q;
                float ax = q.x - v.x, ay = q.y - v.y, az = q.z - v.z, aw = q.w - v.w;
                errp += ax * ax + ay * ay + az * az + aw * aw;
            } else if (fr == 0) {
                unsigned pos = atomicAdd(counter, 1u);
                list[pos] = (unsigned)row;      // fallback writes out + err
            }
        }
    }

    // deterministic block err reduce -> one fixed-point atomic
    __syncthreads();
    redE[tid] = errp;
    __syncthreads();
    for (int s = 128; s > 0; s >>= 1) {
        if (tid < s) redE[tid] += redE[tid + s];
        __syncthreads();
    }
    if (tid == 0)
        atomicAdd(errAcc, (u64)((double)redE[0] * FXS + 0.5));
}

// ---------- exact fallback: full 1024-code scan, R1 form; writes out + err --
__global__ __launch_bounds__(256) void vq_fallback(const float* __restrict__ x,
                                                   const float* __restrict__ emb,
                                                   const float* __restrict__ enorm,
                                                   const unsigned* __restrict__ list,
                                                   const unsigned* __restrict__ counter,
                                                   float* __restrict__ out,
                                                   u64* __restrict__ errAcc) {
    __shared__ float4 xr[16];
    __shared__ u64 red[256];
    __shared__ float errv[16];
    const int tid = threadIdx.x;
    const unsigned total = counter[0];
    u64 qerr = 0ull;
    for (unsigned i = blockIdx.x; i < total; i += gridDim.x) {
        const int n = (int)list[i];
        __syncthreads();
        if (tid < 16) xr[tid] = ((const float4*)x)[(size_t)n * 16 + tid];
        __syncthreads();
        float xnorm = 0.f;                     // R1-order xnorm
        #pragma unroll
        for (int q = 0; q < 16; ++q) {
            float4 v = xr[q];
            xnorm += v.x * v.x + v.y * v.y + v.z * v.z + v.w * v.w;
        }
        u64 best = ~0ull;
        #pragma unroll
        for (int j = 0; j < 4; ++j) {
            int k = tid + j * 256;
            const float4* e4 = (const float4*)(emb + (size_t)k * D);
            float d0 = 0.f, d1v = 0.f, d2v = 0.f, d3v = 0.f;
            #pragma unroll
            for (int q = 0; q < 4; ++q) {      // proven R1 4-chain ordering
                float4 ea = e4[q*4+0], eb = e4[q*4+1], ec = e4[q*4+2], ed = e4[q*4+3];
                float4 va = xr[q*4+0], vb = xr[q*4+1], vc = xr[q*4+2], vd = xr[q*4+3];
                d0  = fmaf(va.w, ea.w, fmaf(va.z, ea.z, fmaf(va.y, ea.y, fmaf(va.x, ea.x, d0))));
                d1v = fmaf(vb.w, eb.w, fmaf(vb.z, eb.z, fmaf(vb.y, eb.y, fmaf(vb.x, eb.x, d1v))));
                d2v = fmaf(vc.w, ec.w, fmaf(vc.z, ec.z, fmaf(vc.y, ec.y, fmaf(vc.x, ec.x, d2v))));
                d3v = fmaf(vd.w, ed.w, fmaf(vd.z, ed.z, fmaf(vd.y, ed.y, fmaf(vd.x, ed.x, d3v))));
            }
            float dot  = (d0 + d1v) + (d2v + d3v);
            float dist = fmaf(-2.f, dot, xnorm + enorm[k]);
            u64 pk = ((u64)ordf(dist) << 32) | (unsigned)k;
            if (pk < best) best = pk;          // dist-then-lowest-idx
        }
        red[tid] = best;
        __syncthreads();
        for (int s = 128; s > 0; s >>= 1) {
            if (tid < s) red[tid] = red[tid] < red[tid+s] ? red[tid] : red[tid+s];
            __syncthreads();
        }
        const int bi = (int)(red[0] & 0xFFFFFFFFu);
        if (tid < 16) {                        // write output + per-lane err
            float4 q = ((const float4*)emb)[(size_t)bi * 16 + tid];
            float4 v = xr[tid];
            ((float4*)out)[(size_t)n * 16 + tid] = q;
            float ax = q.x - v.x, ay = q.y - v.y, az = q.z - v.z, aw = q.w - v.w;
            errv[tid] = ax * ax + ay * ay + az * az + aw * aw;
        }
        __syncthreads();
        if (tid == 0) {                        // deterministic fixed-order sum
            float re = 0.f;
            #pragma unroll
            for (int j = 0; j < 16; ++j) re += errv[j];
            qerr += (u64)((double)re * FXS + 0.5);
        }
    }
    if (tid == 0 && qerr) atomicAdd(errAcc, qerr);
}

// ------------------------------------------------------------- finalize ----
__global__ __launch_bounds__(64) void vq_finish(const u64* __restrict__ errAcc,
                                                float* __restrict__ loss_out) {
    if (threadIdx.x == 0) {
        double s = (double)errAcc[0] / FXS;
        loss_out[0] = (float)((1.0 + (double)BETA) * s / (double)((size_t)NROWS * D));
    }
}

// ---------------------------------------------------------------- launch ---
extern "C" void kernel_launch(void* const* d_in, const int* in_sizes, int n_in,
                              void* d_out, int out_size, void* d_ws, size_t ws_size,
                              hipStream_t stream) {
    const float* x   = (const float*)d_in[0];
    const float* emb = (const float*)d_in[1];
    float* out = (float*)d_out;
    char* ws = (char*)d_ws;

    char* Bp          = ws + WS_BP;
    float* enorm      = (float*)(ws + WS_EN);
    float* enorm2     = (float*)(ws + WS_EN2);
    unsigned* list    = (unsigned*)(ws + WS_LIST);
    unsigned* counter = (unsigned*)(ws + WS_CNT);
    u64* errAcc       = (u64*)(ws + WS_ERR);

    vq_prep<<<K / 256, 256, 0, stream>>>(emb, enorm, enorm2, Bp, counter, errAcc);
    vq_gemm<<<NROWS / BR, 256, 0, stream>>>(x, Bp, emb, enorm2, out, list, counter, errAcc);
    vq_fallback<<<128, 256, 0, stream>>>(x, emb, enorm, list, counter, out, errAcc);
    vq_finish<<<1, 64, 0, stream>>>(errAcc, out + (size_t)NROWS * D);
}

// Round 24
// 60.455 us; speedup vs baseline: 1.2784x; 1.0212x over previous
//
#include <hip/hip_runtime.h>
#include <math.h>

#define NROWS 65536
#define D     64
#define K     1024
#define NCT   8            // code tiles (K/128)
#define BR    128
#define BC    128
#define BETA  0.25f
#define SCALE 1024.0f      // pow2 -> exact f32 scaling; keeps xl/el f16-normal
#define THR   200.0f       // scaled-dist margin (R15-proven)
#define FXS   1048576.0    // fixed-point scale 2^20 for deterministic loss sum
#define FBGRID 128

typedef _Float16 half8  __attribute__((ext_vector_type(8)));
typedef float    f32x4  __attribute__((ext_vector_type(4)));
typedef unsigned long long u64;

// ws layout (bytes)
#define WS_BP   0u                         // 8 tiles x 32 KB = 256 KB (LDS image, swizzled)
#define WS_EN   (256u*1024)                // f32 [K] enorm (4 KB)
#define WS_EN2  (260u*1024)                // f32 [K] enorm*S^2 (4 KB)
#define WS_LIST (264u*1024)                // u32 [NROWS] (256 KB)
#define WS_CNT  (WS_LIST + 256u*1024)      // u32 [0]=fallback count, [1]=done count (pad 128)
#define WS_ERR  (WS_CNT + 128u)            // u64 fixed-point err accumulator

static __device__ __forceinline__ unsigned ordf(float f) {
    unsigned b = __float_as_uint(f);
    return (b & 0x80000000u) ? ~b : (b | 0x80000000u);
}
static __device__ __forceinline__ void gload_lds16(const void* g, void* l) {
    __builtin_amdgcn_global_load_lds(
        (const __attribute__((address_space(1))) unsigned*)g,
        (__attribute__((address_space(3))) unsigned*)l,
        16, 0, 0);
}

// -------- prep (8x parallel): chunk-per-thread packing + R1-order enorm ----
// 8192 threads (32 blocks): thread -> (code k = gid>>3, chunk c = gid&7).
// enorm MUST keep R1's serial summation order (R9: reordering flips near-tie
// argmin decisions) -> the c==0 lane of each code computes it alone; its 16
// loads share cache lines with sibling lanes' packing loads.
__global__ __launch_bounds__(256) void vq_prep(const float* __restrict__ emb,
                                               float* __restrict__ enorm,
                                               float* __restrict__ enorm2,
                                               char* __restrict__ Bp,
                                               unsigned* __restrict__ counter,
                                               u64* __restrict__ errAcc) {
    const int gid = blockIdx.x * 256 + threadIdx.x;       // 0..8191
    if (gid == 0) { counter[0] = 0u; counter[1] = 0u; errAcc[0] = 0ull; }
    const int k  = gid >> 3;
    const int c  = gid & 7;
    const int ct = k >> 7, r = k & 127;
    const float4* e4 = (const float4*)(emb + (size_t)k * D);

    // pack chunk c (f16 elems 8c..8c+7) into the swizzled LDS image
    float4 ea = e4[2 * c], eb = e4[2 * c + 1];
    float sc[8] = {ea.x * SCALE, ea.y * SCALE, ea.z * SCALE, ea.w * SCALE,
                   eb.x * SCALE, eb.y * SCALE, eb.z * SCALE, eb.w * SCALE};
    half8 hh, hl;
    #pragma unroll
    for (int e = 0; e < 8; ++e) {
        _Float16 h = (_Float16)sc[e];
        hh[e] = h;
        hl[e] = (_Float16)(sc[e] - (float)h);
    }
    char* base = Bp + (size_t)ct * 32768 + (size_t)r * 128;
    int off = ((c ^ (r & 7)) << 4);
    *(half8*)(base + off)         = hh;     // eh
    *(half8*)(base + 16384 + off) = hl;     // el

    if (c == 0) {                           // R1-order serial enorm (exact)
        float s = 0.f;
        #pragma unroll
        for (int i = 0; i < 16; ++i) {
            float4 v = e4[i];
            s += v.x * v.x + v.y * v.y + v.z * v.z + v.w * v.w;
        }
        enorm[k]  = s;
        enorm2[k] = s * (SCALE * SCALE);    // pow2 mul: exact
    }
}

// --------------- MFMA filter (R23, passed) — unchanged -------------------
__global__ __launch_bounds__(256, 2) void vq_gemm(const float* __restrict__ x,
                                                  const char* __restrict__ Bp,
                                                  const float* __restrict__ emb,
                                                  const float* __restrict__ enorm2,
                                                  float* __restrict__ out,
                                                  unsigned* __restrict__ list,
                                                  unsigned* __restrict__ counter,
                                                  u64* __restrict__ errAcc) {
    __shared__ __align__(16) char bufB[2][32768];   // 64 KB double buffer
    __shared__ float lds_en2[K];                    // 4 KB
    __shared__ float redE[256];                     // 1 KB

    const int tid  = threadIdx.x;
    const int lane = tid & 63, w = tid >> 6;
    const int fr   = lane & 15;                // frag row (A) / frag col (B)
    const int kg   = lane >> 4;                // k-group 0..3
    const int rb   = (int)blockIdx.x * BR;

    // ---- A fragments: direct global load + scale/split in registers ----
    const float4* x4 = (const float4*)x;
    half8 ah[2][2], al[2][2];
    #pragma unroll
    for (int fi = 0; fi < 2; ++fi) {
        #pragma unroll
        for (int kk = 0; kk < 2; ++kk) {
            int row = rb + w * 32 + fi * 16 + fr;
            float4 v0 = x4[(size_t)row * 16 + kk * 8 + kg * 2];
            float4 v1 = x4[(size_t)row * 16 + kk * 8 + kg * 2 + 1];
            float sc[8] = {v0.x * SCALE, v0.y * SCALE, v0.z * SCALE, v0.w * SCALE,
                           v1.x * SCALE, v1.y * SCALE, v1.z * SCALE, v1.w * SCALE};
            #pragma unroll
            for (int e = 0; e < 8; ++e) {
                _Float16 h = (_Float16)sc[e];
                ah[fi][kk][e] = h;
                al[fi][kk][e] = (_Float16)(sc[e] - (float)h);
            }
        }
    }

    // ---- prologue: stage enorm2 to LDS (only vmem before loop), drain ----
    lds_en2[tid]       = enorm2[tid];
    lds_en2[tid + 256] = enorm2[tid + 256];
    lds_en2[tid + 512] = enorm2[tid + 512];
    lds_en2[tid + 768] = enorm2[tid + 768];
    __syncthreads();                           // full drain: nothing else in flight

    // ---- issue prefetch of B tile 0 (8 gload_lds / wave) ----
    {
        const char* gsrc = Bp + (size_t)w * 8192 + (size_t)lane * 16;
        char* ldst = &bufB[0][w * 8192];
        #pragma unroll
        for (int j = 0; j < 8; ++j)
            gload_lds16(gsrc + j * 1024, ldst + j * 1024);
    }

    // running top-2 state per (fi,rg): exact f32 dists + best idx
    float d1[2][4], d2[2][4];
    int   i1[2][4];
    #pragma unroll
    for (int fi = 0; fi < 2; ++fi)
        #pragma unroll
        for (int rg = 0; rg < 4; ++rg) {
            d1[fi][rg] = 3.4e38f; d2[fi][rg] = 3.4e38f; i1[fi][rg] = 0;
        }

    for (int ct = 0; ct < NCT; ++ct) {
        const int  cb  = ct * BC;
        const int  buf = ct & 1;

        __builtin_amdgcn_s_barrier();          // all waves done reading buf^1
        if (ct < NCT - 1) {                    // issue prefetch ct+1 -> buf^1
            const char* gsrc = Bp + (size_t)(ct + 1) * 32768 + (size_t)w * 8192
                             + (size_t)lane * 16;
            char* ldst = &bufB[buf ^ 1][w * 8192];
            #pragma unroll
            for (int j = 0; j < 8; ++j)
                gload_lds16(gsrc + j * 1024, ldst + j * 1024);
            asm volatile("s_waitcnt vmcnt(8)" ::: "memory");   // retire tile ct only
        } else {
            asm volatile("s_waitcnt vmcnt(0)" ::: "memory");
        }
        __builtin_amdgcn_s_barrier();          // tile ct landed for every wave
        __builtin_amdgcn_sched_barrier(0);

        float en2f[8];
        #pragma unroll
        for (int ci = 0; ci < 8; ++ci)
            en2f[ci] = lds_en2[cb + ci * 16 + fr];
        const int idxb = cb + fr;

        const char* bb = &bufB[buf][0];

        #pragma unroll
        for (int g = 0; g < 2; ++g) {          // ci-groups of 4 (caps VGPR)
            f32x4 acc[2][4];
            #pragma unroll
            for (int fi = 0; fi < 2; ++fi)
                #pragma unroll
                for (int i = 0; i < 4; ++i) acc[fi][i] = (f32x4){0.f, 0.f, 0.f, 0.f};

            #pragma unroll
            for (int kk = 0; kk < 2; ++kk) {
                const int chunk = ((kk * 4 + kg) ^ (fr & 7)) << 4;
                half8 bf[4];
                #pragma unroll
                for (int i = 0; i < 4; ++i)    // bh frags (swizzled, conflict-free)
                    bf[i] = *(const half8*)(bb + ((g * 4 + i) * 16 + fr) * 128 + chunk);
                #pragma unroll                 // 8 independent, then dependents at dist 8
                for (int fi = 0; fi < 2; ++fi)
                    #pragma unroll
                    for (int i = 0; i < 4; ++i)
                        acc[fi][i] = __builtin_amdgcn_mfma_f32_16x16x32_f16(ah[fi][kk], bf[i], acc[fi][i], 0, 0, 0);
                #pragma unroll
                for (int fi = 0; fi < 2; ++fi)
                    #pragma unroll
                    for (int i = 0; i < 4; ++i)
                        acc[fi][i] = __builtin_amdgcn_mfma_f32_16x16x32_f16(al[fi][kk], bf[i], acc[fi][i], 0, 0, 0);
                #pragma unroll
                for (int i = 0; i < 4; ++i)    // bl frags
                    bf[i] = *(const half8*)(bb + 16384 + ((g * 4 + i) * 16 + fr) * 128 + chunk);
                #pragma unroll
                for (int fi = 0; fi < 2; ++fi)
                    #pragma unroll
                    for (int i = 0; i < 4; ++i)
                        acc[fi][i] = __builtin_amdgcn_mfma_f32_16x16x32_f16(ah[fi][kk], bf[i], acc[fi][i], 0, 0, 0);
            }

            // f32 streaming top-2 update (ci ascending; strict < tiebreak)
            #pragma unroll
            for (int fi = 0; fi < 2; ++fi) {
                #pragma unroll
                for (int rg = 0; rg < 4; ++rg) {
                    #pragma unroll
                    for (int i = 0; i < 4; ++i) {
                        float d  = fmaf(-2.f, acc[fi][i][rg], en2f[g * 4 + i]);
                        int  idx = idxb + (g * 4 + i) * 16;
                        bool lt  = d < d1[fi][rg];
                        d2[fi][rg] = fminf(fmaxf(d1[fi][rg], d), d2[fi][rg]);
                        i1[fi][rg] = lt ? idx : i1[fi][rg];
                        d1[fi][rg] = fminf(d1[fi][rg], d);
                    }
                }
            }
        }
    }

    // ---- fused epilogue: butterfly, margin test, output write, err accum --
    const float4* e4g = (const float4*)emb;
    float4* o4 = (float4*)out;
    float errp = 0.f;
    #pragma unroll
    for (int fi = 0; fi < 2; ++fi) {
        #pragma unroll
        for (int rg = 0; rg < 4; ++rg) {
            float v1 = d1[fi][rg], v2 = d2[fi][rg];
            int   ii = i1[fi][rg];
            #pragma unroll
            for (int off = 8; off >= 1; off >>= 1) {
                float o1 = __shfl_xor(v1, off, 16);
                float o2 = __shfl_xor(v2, off, 16);
                int   oi = __shfl_xor(ii, off, 16);
                float loser = fmaxf(v1, o1);
                v2 = fminf(fminf(v2, o2), loser);
                bool bt = o1 < v1;              // exact tie -> margin fails anyway
                v1 = fminf(v1, o1);
                ii = bt ? oi : ii;
            }
            int row = rb + w * 32 + fi * 16 + kg * 4 + rg;
            if (v2 - v1 > THR) {                // provably ref argmin: write output
                float4 q = e4g[(size_t)ii * 16 + fr];
                float4 v = x4[(size_t)row * 16 + fr];
                o4[(size_t)row * 16 + fr] = q;
                float ax = q.x - v.x, ay = q.y - v.y, az = q.z - v.z, aw = q.w - v.w;
                errp += ax * ax + ay * ay + az * az + aw * aw;
            } else if (fr == 0) {
                unsigned pos = atomicAdd(counter, 1u);
                list[pos] = (unsigned)row;      // fallback writes out + err
            }
        }
    }

    // deterministic block err reduce -> one fixed-point atomic
    __syncthreads();
    redE[tid] = errp;
    __syncthreads();
    for (int s = 128; s > 0; s >>= 1) {
        if (tid < s) redE[tid] += redE[tid + s];
        __syncthreads();
    }
    if (tid == 0)
        atomicAdd(errAcc, (u64)((double)redE[0] * FXS + 0.5));
}

// ---- exact fallback (R1 form) + fused finalize via last-block-done --------
__global__ __launch_bounds__(256) void vq_fallback(const float* __restrict__ x,
                                                   const float* __restrict__ emb,
                                                   const float* __restrict__ enorm,
                                                   const unsigned* __restrict__ list,
                                                   unsigned* __restrict__ counter,
                                                   float* __restrict__ out,
                                                   u64* __restrict__ errAcc) {
    __shared__ float4 xr[16];
    __shared__ u64 red[256];
    __shared__ float errv[16];
    const int tid = threadIdx.x;
    const unsigned total = counter[0];
    u64 qerr = 0ull;
    for (unsigned i = blockIdx.x; i < total; i += gridDim.x) {
        const int n = (int)list[i];
        __syncthreads();
        if (tid < 16) xr[tid] = ((const float4*)x)[(size_t)n * 16 + tid];
        __syncthreads();
        float xnorm = 0.f;                     // R1-order xnorm
        #pragma unroll
        for (int q = 0; q < 16; ++q) {
            float4 v = xr[q];
            xnorm += v.x * v.x + v.y * v.y + v.z * v.z + v.w * v.w;
        }
        u64 best = ~0ull;
        #pragma unroll
        for (int j = 0; j < 4; ++j) {
            int k = tid + j * 256;
            const float4* e4 = (const float4*)(emb + (size_t)k * D);
            float d0 = 0.f, d1v = 0.f, d2v = 0.f, d3v = 0.f;
            #pragma unroll
            for (int q = 0; q < 4; ++q) {      // proven R1 4-chain ordering
                float4 ea = e4[q*4+0], eb = e4[q*4+1], ec = e4[q*4+2], ed = e4[q*4+3];
                float4 va = xr[q*4+0], vb = xr[q*4+1], vc = xr[q*4+2], vd = xr[q*4+3];
                d0  = fmaf(va.w, ea.w, fmaf(va.z, ea.z, fmaf(va.y, ea.y, fmaf(va.x, ea.x, d0))));
                d1v = fmaf(vb.w, eb.w, fmaf(vb.z, eb.z, fmaf(vb.y, eb.y, fmaf(vb.x, eb.x, d1v))));
                d2v = fmaf(vc.w, ec.w, fmaf(vc.z, ec.z, fmaf(vc.y, ec.y, fmaf(vc.x, ec.x, d2v))));
                d3v = fmaf(vd.w, ed.w, fmaf(vd.z, ed.z, fmaf(vd.y, ed.y, fmaf(vd.x, ed.x, d3v))));
            }
            float dot  = (d0 + d1v) + (d2v + d3v);
            float dist = fmaf(-2.f, dot, xnorm + enorm[k]);
            u64 pk = ((u64)ordf(dist) << 32) | (unsigned)k;
            if (pk < best) best = pk;          // dist-then-lowest-idx
        }
        red[tid] = best;
        __syncthreads();
        for (int s = 128; s > 0; s >>= 1) {
            if (tid < s) red[tid] = red[tid] < red[tid+s] ? red[tid] : red[tid+s];
            __syncthreads();
        }
        const int bi = (int)(red[0] & 0xFFFFFFFFu);
        if (tid < 16) {                        // write output + per-lane err
            float4 q = ((const float4*)emb)[(size_t)bi * 16 + tid];
            float4 v = xr[tid];
            ((float4*)out)[(size_t)n * 16 + tid] = q;
            float ax = q.x - v.x, ay = q.y - v.y, az = q.z - v.z, aw = q.w - v.w;
            errv[tid] = ax * ax + ay * ay + az * az + aw * aw;
        }
        __syncthreads();
        if (tid == 0) {                        // deterministic fixed-order sum
            float re = 0.f;
            #pragma unroll
            for (int j = 0; j < 16; ++j) re += errv[j];
            qerr += (u64)((double)re * FXS + 0.5);
        }
    }

    // fused finalize: last finished block computes the loss
    __syncthreads();
    if (tid == 0) {
        if (qerr) atomicAdd(errAcc, qerr);
        __threadfence();                       // errAcc visible before done++
        unsigned prev = atomicAdd(&counter[1], 1u);
        if (prev == (unsigned)gridDim.x - 1u) {
            u64 te = atomicAdd(errAcc, 0ull);  // coherent device-scope read
            double s = (double)te / FXS;
            out[(size_t)NROWS * D] =
                (float)((1.0 + (double)BETA) * s / (double)((size_t)NROWS * D));
        }
    }
}

// ---------------------------------------------------------------- launch ---
extern "C" void kernel_launch(void* const* d_in, const int* in_sizes, int n_in,
                              void* d_out, int out_size, void* d_ws, size_t ws_size,
                              hipStream_t stream) {
    const float* x   = (const float*)d_in[0];
    const float* emb = (const float*)d_in[1];
    float* out = (float*)d_out;
    char* ws = (char*)d_ws;

    char* Bp          = ws + WS_BP;
    float* enorm      = (float*)(ws + WS_EN);
    float* enorm2     = (float*)(ws + WS_EN2);
    unsigned* list    = (unsigned*)(ws + WS_LIST);
    unsigned* counter = (unsigned*)(ws + WS_CNT);
    u64* errAcc       = (u64*)(ws + WS_ERR);

    vq_prep<<<32, 256, 0, stream>>>(emb, enorm, enorm2, Bp, counter, errAcc);
    vq_gemm<<<NROWS / BR, 256, 0, stream>>>(x, Bp, emb, enorm2, out, list, counter, errAcc);
    vq_fallback<<<FBGRID, 256, 0, stream>>>(x, emb, enorm, list, counter, out, errAcc);
}